// Round 4
// baseline (165.064 us; speedup 1.0000x reference)
//
#include <hip/hip_runtime.h>

// PyramidToDepth: x (8,512,512,2) fp32 -> out (8,18,512,512,1) fp32
// levels lv=0..8, S=512>>lv; out[b, 2*lv+c, h, w] = bilinear_up(level_lv)[b,h,w,c]
//
// d_ws holds levels 2..6 only (lv1 never touches global), float2-unit offsets
// (unchanged historical layout): lv2 @524288, lv3 @655360, lv4 @688128,
// lv5 @696320, lv6 @698368.
//
// Round theory: (1) build -> 512 thr/block (32 waves/CU) so the x read is
// BW-bound not latency-bound; (2) build stages a 34x34 halo'd lv1 window in
// LDS (skewed), emits lv0 during staging, and produces the lv1-upsampled
// output region directly (constant {0.25,0.75} weights) -- lv1 is never
// written to / read from HBM; (3) upsample kernel handles only lv2..8.

#define HWTOT (512 * 512)
#define SW 40   // skewed lv1-window row stride (f2): 34 cols + skew <= 38
#define RW 132  // B-kernel LDS row stride (f2): max W = 130 (lv2)

typedef float vfloat4 __attribute__((ext_vector_type(4)));

__constant__ int c_off2[7] = {0, 0, 524288, 655360, 688128, 696320, 698368};

// --- Kernel A: lv0 + lv1-upsample + pyramid lv2..6. grid (64,8) x 512 thr. --
// Block owns a 64x64 x-tile == 64x64 output region == 32x32 lv1 tile.
__global__ __launch_bounds__(512) void build_all(const float* __restrict__ x,
                                                 float2* __restrict__ pyr,
                                                 float* __restrict__ out) {
  const int b = blockIdx.y;
  const int tx = blockIdx.x & 7, ty = blockIdx.x >> 3;
  const int t = threadIdx.x;

  __shared__ float2 sh1[34 * SW];  // lv1 window rows -1..32, cols -1..32, skewed
  __shared__ float2 sh2[16 * 16];
  __shared__ float2 sh3[8 * 8];
  __shared__ float2 sh4[4 * 4];
  __shared__ float2 sh5[2 * 2];

  // Phase 1: stage 34x34 halo'd lv1 window (halo: clamp at lv1-row/col level,
  // matching the old gather's clamp semantics bit-for-bit) + lv0 passthrough.
  for (int idx = t; idx < 34 * 34; idx += 512) {
    const int jw = idx / 34;         // window row 0..33  (lv1 local row jw-1)
    const int iw = idx - jw * 34;    // window col 0..33  (lv1 local col iw-1)
    int jl = ty * 32 + jw - 1;
    jl = jl < 0 ? 0 : (jl > 255 ? 255 : jl);
    int il = tx * 32 + iw - 1;
    il = il < 0 ? 0 : (il > 255 ? 255 : il);
    const float* p0 = x + ((size_t)(b * 512 + 2 * jl) * 512 + 2 * il) * 2;
    float4 a = *(const float4*)p0;          // x rows 2jl, cols 2il..2il+1
    float4 c = *(const float4*)(p0 + 1024); // x row 2jl+1
    sh1[jw * SW + iw + (iw >> 3)] = {(a.x + a.z + c.x + c.z) * 0.25f,
                                     (a.y + a.w + c.y + c.w) * 0.25f};
    if (jw >= 1 && jw <= 32 && iw >= 1 && iw <= 32) {  // interior: emit lv0
      const int xr = 2 * jl, xc = 2 * il;
      const size_t ob = (size_t)(b * 18) * HWTOT + (size_t)xr * 512 + xc;
      *(float2*)(out + ob) = {a.x, a.z};
      *(float2*)(out + ob + 512) = {c.x, c.z};
      *(float2*)(out + ob + HWTOT) = {a.y, a.w};
      *(float2*)(out + ob + HWTOT + 512) = {c.y, c.w};
    }
  }
  __syncthreads();

  // Phase 2: lv1-upsampled output region 64x64 x 2ch from the LDS window.
  // out local col c: src cols (c-1)>>1, +1 -> window cols 2g..2g+3 for the
  // 4-px group; weights constant {0.25,0.75}. Same formulas as old fast path.
  {
    const int g = t & 15;    // out cols 4g..4g+3
    const int r0_ = t >> 4;  // out rows r0_, r0_+32
    const int e0 = g << 1;
    const int i0 = e0 + (e0 >> 3);
    const int i1 = (e0 + 1) + ((e0 + 1) >> 3);
    const int i2 = (e0 + 2) + ((e0 + 2) >> 3);
    const int i3 = (e0 + 3) + ((e0 + 3) >> 3);
#pragma unroll
    for (int pass = 0; pass < 2; ++pass) {
      const int R = r0_ + pass * 32;          // out local row
      const int wr = ((R - 1) >> 1) + 1;      // window row of upper tap
      const float fh = (R & 1) ? 0.25f : 0.75f;
      const float wy0 = 1.0f - fh;
      const float2* P = sh1 + wr * SW;
      const float2* Q = P + SW;
      float2 p0 = P[i0], p1 = P[i1], p2 = P[i2], p3 = P[i3];
      float2 q0 = Q[i0], q1 = Q[i1], q2 = Q[i2], q3 = Q[i3];
      float hx0 = p0.x * 0.25f + p1.x * 0.75f, hy0 = p0.y * 0.25f + p1.y * 0.75f;
      float hx1 = p1.x * 0.75f + p2.x * 0.25f, hy1 = p1.y * 0.75f + p2.y * 0.25f;
      float hx2 = p1.x * 0.25f + p2.x * 0.75f, hy2 = p1.y * 0.25f + p2.y * 0.75f;
      float hx3 = p2.x * 0.75f + p3.x * 0.25f, hy3 = p2.y * 0.75f + p3.y * 0.25f;
      float gx0 = q0.x * 0.25f + q1.x * 0.75f, gy0 = q0.y * 0.25f + q1.y * 0.75f;
      float gx1 = q1.x * 0.75f + q2.x * 0.25f, gy1 = q1.y * 0.75f + q2.y * 0.25f;
      float gx2 = q1.x * 0.25f + q2.x * 0.75f, gy2 = q1.y * 0.25f + q2.y * 0.75f;
      float gx3 = q2.x * 0.75f + q3.x * 0.25f, gy3 = q2.y * 0.75f + q3.y * 0.25f;
      const size_t ob =
          (size_t)(b * 18 + 2) * HWTOT + (size_t)(ty * 64 + R) * 512 + tx * 64 + 4 * g;
      *(vfloat4*)(out + ob) = (vfloat4){hx0 * wy0 + gx0 * fh, hx1 * wy0 + gx1 * fh,
                                        hx2 * wy0 + gx2 * fh, hx3 * wy0 + gx3 * fh};
      *(vfloat4*)(out + ob + HWTOT) = (vfloat4){hy0 * wy0 + gy0 * fh, hy1 * wy0 + gy1 * fh,
                                                hy2 * wy0 + gy2 * fh, hy3 * wy0 + gy3 * fh};
    }
  }

  // Chain lv2..6 (reads lv1 from the skewed window; interior only: lv1 local
  // row r -> window row r+1, col c -> window col c+1).
  if (t < 256) {
    const int i = t >> 4, j = t & 15;
    const int ca = (2 * j + 1) + ((2 * j + 1) >> 3);
    const int cb = (2 * j + 2) + ((2 * j + 2) >> 3);
    float2 a = sh1[(2 * i + 1) * SW + ca], c = sh1[(2 * i + 1) * SW + cb];
    float2 d = sh1[(2 * i + 2) * SW + ca], e = sh1[(2 * i + 2) * SW + cb];
    float2 o = {(a.x + c.x + d.x + e.x) * 0.25f, (a.y + c.y + d.y + e.y) * 0.25f};
    sh2[i * 16 + j] = o;
    pyr[524288 + (size_t)(b * 128 + ty * 16 + i) * 128 + tx * 16 + j] = o;
  }
  __syncthreads();
  if (t < 64) {
    const int i = t >> 3, j = t & 7;
    float2 a = sh2[(2 * i) * 16 + 2 * j], c = sh2[(2 * i) * 16 + 2 * j + 1];
    float2 d = sh2[(2 * i + 1) * 16 + 2 * j], e = sh2[(2 * i + 1) * 16 + 2 * j + 1];
    float2 o = {(a.x + c.x + d.x + e.x) * 0.25f, (a.y + c.y + d.y + e.y) * 0.25f};
    sh3[i * 8 + j] = o;
    pyr[655360 + (size_t)(b * 64 + ty * 8 + i) * 64 + tx * 8 + j] = o;
  }
  __syncthreads();
  if (t < 16) {
    const int i = t >> 2, j = t & 3;
    float2 a = sh3[(2 * i) * 8 + 2 * j], c = sh3[(2 * i) * 8 + 2 * j + 1];
    float2 d = sh3[(2 * i + 1) * 8 + 2 * j], e = sh3[(2 * i + 1) * 8 + 2 * j + 1];
    float2 o = {(a.x + c.x + d.x + e.x) * 0.25f, (a.y + c.y + d.y + e.y) * 0.25f};
    sh4[i * 4 + j] = o;
    pyr[688128 + (size_t)(b * 32 + ty * 4 + i) * 32 + tx * 4 + j] = o;
  }
  __syncthreads();
  if (t < 4) {
    const int i = t >> 1, j = t & 1;
    float2 a = sh4[(2 * i) * 4 + 2 * j], c = sh4[(2 * i) * 4 + 2 * j + 1];
    float2 d = sh4[(2 * i + 1) * 4 + 2 * j], e = sh4[(2 * i + 1) * 4 + 2 * j + 1];
    float2 o = {(a.x + c.x + d.x + e.x) * 0.25f, (a.y + c.y + d.y + e.y) * 0.25f};
    sh5[i * 2 + j] = o;
    pyr[696320 + (size_t)(b * 16 + ty * 2 + i) * 16 + tx * 2 + j] = o;
  }
  __syncthreads();
  if (t == 0) {
    float2 a = sh5[0], c = sh5[1], d = sh5[2], e = sh5[3];
    float2 o = {(a.x + c.x + d.x + e.x) * 0.25f, (a.y + c.y + d.y + e.y) * 0.25f};
    pyr[698368 + (size_t)(b * 8 + ty) * 8 + tx] = o;
  }
}

// --- Kernel B: levels 2..8, blockIdx.z = lv-2; 8 output rows per block. -----
// LDS: 6-row x (S+2)-col window, col-shifted by +1 with edge clamps baked in:
// rows[r][c] = src[clamp(hbase+r)][clamp(c-1)]. Gather needs no clamps.
__global__ __launch_bounds__(256) void upsample_lv(const float2* __restrict__ pyr,
                                                   float* __restrict__ out) {
  const int t = threadIdx.x;
  const int tp = t & 127;  // pixels 4*tp..4*tp+3
  const int rr0 = t >> 7;  // 0/1
  const int w0pix = tp << 2;
  const int bx = blockIdx.x;  // rows 8*bx..8*bx+7
  const int b = blockIdx.y;
  const int lv = blockIdx.z + 2;  // 2..8, block-uniform
  const int S = 512 >> lv;
  const float scale = 1.0f / (float)(1 << lv);

  __shared__ float2 rows[6 * RW + 20];  // window + img7(16) + img8(4)

  const int W = S + 2;
  const int hbase = (int)floorf(((float)(bx << 3) + 0.5f) * scale - 0.5f);

  if (lv <= 6) {
#pragma unroll
    for (int r = 0; r < 6; ++r) {
      int sr = hbase + r;
      sr = sr < 0 ? 0 : (sr > S - 1 ? S - 1 : sr);
      const float2* src = pyr + c_off2[lv] + (size_t)b * S * S + (size_t)sr * S;
      if (t < W) {  // W <= 130
        int sc = t - 1;
        sc = sc < 0 ? 0 : (sc > S - 1 ? S - 1 : sc);
        rows[r * RW + t] = src[sc];
      }
    }
  } else {
    // rebuild lv7 (and lv8) from lv6; block-uniform branches -> sync safe
    float2* img7 = rows + 6 * RW;
    float2* img8 = img7 + 16;
    const float2* l6 = pyr + 698368 + (size_t)b * 64;
    if (t < 16) {
      const int i = t >> 2, j = t & 3;
      float2 a = l6[(2 * i) * 8 + 2 * j], c = l6[(2 * i) * 8 + 2 * j + 1];
      float2 d = l6[(2 * i + 1) * 8 + 2 * j], e = l6[(2 * i + 1) * 8 + 2 * j + 1];
      img7[t] = {(a.x + c.x + d.x + e.x) * 0.25f, (a.y + c.y + d.y + e.y) * 0.25f};
    }
    __syncthreads();
    if (lv == 8 && t < 4) {
      const int i = t >> 1, j = t & 1;
      float2 a = img7[(2 * i) * 4 + 2 * j], c = img7[(2 * i) * 4 + 2 * j + 1];
      float2 d = img7[(2 * i + 1) * 4 + 2 * j], e = img7[(2 * i + 1) * 4 + 2 * j + 1];
      img8[t] = {(a.x + c.x + d.x + e.x) * 0.25f, (a.y + c.y + d.y + e.y) * 0.25f};
    }
    __syncthreads();
    const float2* img = (lv == 7) ? img7 : img8;
    if (t < 6 * W) {  // 36 or 24 entries
      int r = t / W;
      int c = t - r * W;
      int sr = hbase + r;
      sr = sr < 0 ? 0 : (sr > S - 1 ? S - 1 : sr);
      int sc = c - 1;
      sc = sc < 0 ? 0 : (sc > S - 1 ? S - 1 : sc);
      rows[r * RW + c] = img[sr * S + sc];
    }
  }
  __syncthreads();

  const size_t obase0 =
      (size_t)(b * 18 + 2 * lv) * HWTOT + (size_t)((bx << 3) + rr0) * 512 + w0pix;

  // horizontal indices/weights shared across all rows
  int w0l[4];
  float fw[4];
#pragma unroll
  for (int k = 0; k < 4; ++k) {
    float sw = ((float)(w0pix + k) + 0.5f) * scale - 0.5f;
    float f = floorf(sw);
    fw[k] = sw - f;
    w0l[k] = (int)f + 1;  // shifted LDS col; clamps baked into staging
  }
#pragma unroll
  for (int dr2 = 0; dr2 < 4; ++dr2) {
    const int rr = rr0 + 2 * dr2;
    const int h = (bx << 3) + rr;
    float shf = ((float)h + 0.5f) * scale - 0.5f;
    float f0 = floorf(shf);
    float fh = shf - f0;
    int d0 = (int)f0 - hbase;  // 0..4; vertical clamps baked into staging
    const float2* R0 = rows + d0 * RW;
    const float2* R1 = R0 + RW;
    const float wy0 = 1.0f - fh;
    float o0[4], o1[4];
#pragma unroll
    for (int k = 0; k < 4; ++k) {
      float2 v00 = R0[w0l[k]], v01 = R0[w0l[k] + 1];
      float2 v10 = R1[w0l[k]], v11 = R1[w0l[k] + 1];
      float wx0 = 1.0f - fw[k];
      float tx_ = v00.x * wx0 + v01.x * fw[k];
      float bx_ = v10.x * wx0 + v11.x * fw[k];
      float ty_ = v00.y * wx0 + v01.y * fw[k];
      float by_ = v10.y * wx0 + v11.y * fw[k];
      o0[k] = tx_ * wy0 + bx_ * fh;
      o1[k] = ty_ * wy0 + by_ * fh;
    }
    const size_t ob = obase0 + (size_t)dr2 * 1024;
    *(vfloat4*)(out + ob) = (vfloat4){o0[0], o0[1], o0[2], o0[3]};
    *(vfloat4*)(out + ob + HWTOT) = (vfloat4){o1[0], o1[1], o1[2], o1[3]};
  }
}

extern "C" void kernel_launch(void* const* d_in, const int* in_sizes, int n_in,
                              void* d_out, int out_size, void* d_ws, size_t ws_size,
                              hipStream_t stream) {
  const float* x = (const float*)d_in[0];
  float* out = (float*)d_out;
  float2* pyr = (float2*)d_ws;

  build_all<<<dim3(64, 8), 512, 0, stream>>>(x, pyr, out);
  upsample_lv<<<dim3(64, 8, 7), 256, 0, stream>>>(pyr, out);
}